// Round 11
// baseline (107.243 us; speedup 1.0000x reference)
//
#include <hip/hip_runtime.h>

#define NPIX 4096
#define NCH 72
#define NCHUNK 18
#define KPAD 96

static constexpr float SCALE_LOG2E = 0.022542110013890054f; // (1/64)*log2(e)
static constexpr float SCALE_N = 0.015625f;                 // 1/64

// ws layout (float offsets)
#define OFF_QC 0          // [18][4096][4] f32 chunk q, scaled 1/64
#define OFF_KC 294912     // [18][4096][4] f32 chunk k
#define OFF_VC 589824     // [18][4096][4] f32 chunk v
#define OFF_VG 884736     // [72][4096] f32 global v (c-major)
#define OFF_DG 1179648    // [4096] f32 (atomics; memset)
#define OFF_OUTG 1183744  // [72][4096] f32 (atomics; memset; contiguous with DG)
#define OFF_QB 1478656    // bf16 [4096][96] global q (scaled, zero-padded 72..95)
#define OFF_KB 1675264    // bf16 [4096][96] global k (zero-padded)
#define OFF_WB 1871872    // bf16 [80][4096] global v/D (rows 72..79 zero)
#define OFF_SM 2035712    // [18][16] chunk K-moments: S1(4), S2'(10, diag 1/2-folded) (atomics; memset)
#define OFF_WM 2036000    // [18][64] chunk W-moments: per c<4: [M0, M1(4), M2'(10)] = 15 (atomics; memset)
#define WS_FLOATS 2037152

typedef __attribute__((ext_vector_type(8))) short short8v;
typedef __attribute__((ext_vector_type(4))) float f32x4;

__device__ __forceinline__ float fexp2(float x) {
#if __has_builtin(__builtin_amdgcn_exp2f)
  return __builtin_amdgcn_exp2f(x);
#else
  return exp2f(x);
#endif
}

__device__ __forceinline__ unsigned short bf16r(float f) {
  unsigned int u = __float_as_uint(f);
  u = (u + 0x7FFFu + ((u >> 16) & 1u)) >> 16;
  return (unsigned short)u;
}
__device__ __forceinline__ unsigned int bf16pair(float lo, float hi) {
  return (unsigned int)bf16r(lo) | ((unsigned int)bf16r(hi) << 16);
}

__device__ __forceinline__ f32x4 MFMA(short8v a, short8v b, f32x4 c) {
  return __builtin_amdgcn_mfma_f32_16x16x32_bf16(a, b, c, 0, 0, 0);
}

__device__ __forceinline__ float dot4(float4 a, float4 b) {
  return a.x*b.x + a.y*b.y + a.z*b.z + a.w*b.w;
}

__device__ __forceinline__ float4 mix4(const float* __restrict__ W, const float* __restrict__ b,
                                       float x0, float x1, float x2, float x3, float sc)
{
  float4 r;
  r.x = (b[0] + W[0]*x0  + W[1]*x1  + W[2]*x2  + W[3]*x3)  * sc;
  r.y = (b[1] + W[4]*x0  + W[5]*x1  + W[6]*x2  + W[7]*x3)  * sc;
  r.z = (b[2] + W[8]*x0  + W[9]*x1  + W[10]*x2 + W[11]*x3) * sc;
  r.w = (b[3] + W[12]*x0 + W[13]*x1 + W[14]*x2 + W[15]*x3) * sc;
  return r;
}

// grid (16, 24) x 256. seg 0..5: chunk qkv (3 chunks each, f32). seg 6..23: global (mat m, group of 12)
__global__ __launch_bounds__(256, 3) void k_qkv(const float* __restrict__ x,
    const float* __restrict__ Wq, const float* __restrict__ bq,
    const float* __restrict__ Wk, const float* __restrict__ bk,
    const float* __restrict__ Wv, const float* __restrict__ bv,
    const float* __restrict__ WqG, const float* __restrict__ bqG,
    const float* __restrict__ WkG, const float* __restrict__ bkG,
    const float* __restrict__ WvG, const float* __restrict__ bvG,
    float* __restrict__ ws)
{
  const int p = blockIdx.x * blockDim.x + threadIdx.x;
  const int seg = blockIdx.y;
  if (seg < 6) {
    float4* qd = reinterpret_cast<float4*>(ws + OFF_QC);
    float4* kd = reinterpret_cast<float4*>(ws + OFF_KC);
    float4* vd = reinterpret_cast<float4*>(ws + OFF_VC);
    const int n0 = seg * 3;
#pragma unroll
    for (int dn = 0; dn < 3; ++dn) {
      const int n = n0 + dn;
      const float x0 = x[(4*n+0)*NPIX + p];
      const float x1 = x[(4*n+1)*NPIX + p];
      const float x2 = x[(4*n+2)*NPIX + p];
      const float x3 = x[(4*n+3)*NPIX + p];
      float4 q = mix4(Wq + n*16, bq + n*4, x0, x1, x2, x3, SCALE_N);
      float4 k = mix4(Wk + n*16, bk + n*4, x0, x1, x2, x3, 1.0f);
      float4 v = mix4(Wv + n*16, bv + n*4, x0, x1, x2, x3, 1.0f);
      qd[(size_t)n*NPIX + p] = q;
      kd[(size_t)n*NPIX + p] = k;
      vd[(size_t)n*NPIX + p] = v;
    }
  } else {
    const int m = (seg - 6) / 6;
    const int g6 = (seg - 6) % 6;
    const float* W = (m == 0) ? WqG : (m == 1) ? WkG : WvG;
    const float* b = (m == 0) ? bqG : (m == 1) ? bkG : bvG;
    float4 xv[18];
#pragma unroll
    for (int c = 0; c < 18; ++c) {
      float4 t;
      t.x = x[(4*c+0)*NPIX + p];
      t.y = x[(4*c+1)*NPIX + p];
      t.z = x[(4*c+2)*NPIX + p];
      t.w = x[(4*c+3)*NPIX + p];
      xv[c] = t;
    }
    const int ob = g6 * 12;
    if (m == 2) {
      float* dst = ws + OFF_VG; // [72][4096]
      for (int o = ob; o < ob + 12; ++o) {
        float acc = b[o];
        const float4* wrow = reinterpret_cast<const float4*>(W + o*NCH);
#pragma unroll
        for (int c = 0; c < 18; ++c) acc += dot4(wrow[c], xv[c]);
        dst[o*NPIX + p] = acc;
      }
    } else {
      unsigned short* dst = reinterpret_cast<unsigned short*>(ws + ((m == 0) ? OFF_QB : OFF_KB));
      const float sc = (m == 0) ? SCALE_LOG2E : 1.0f;
      for (int o = ob; o < ob + 12; ++o) {
        float acc = b[o];
        const float4* wrow = reinterpret_cast<const float4*>(W + o*NCH);
#pragma unroll
        for (int c = 0; c < 18; ++c) acc += dot4(wrow[c], xv[c]);
        dst[p*KPAD + o] = bf16r(acc * sc);
      }
      if (g6 == 5) {
#pragma unroll
        for (int o = NCH; o < KPAD; ++o) dst[p*KPAD + o] = 0;
      }
    }
  }
}

// chunk K-moments: SM[n] = [S1(4), S2'(10, diag half)] summed over all i.  grid (4, 18) x 256
__global__ __launch_bounds__(256, 4) void k_kmom(float* __restrict__ ws)
{
  const int n = blockIdx.y;
  const int tid = threadIdx.x;
  const float4* kc = reinterpret_cast<const float4*>(ws + OFF_KC) + (size_t)n*NPIX + blockIdx.x*1024;
  float f[14];
#pragma unroll
  for (int i = 0; i < 14; ++i) f[i] = 0.f;
#pragma unroll
  for (int s = 0; s < 4; ++s) {
    float4 k = kc[s*256 + tid];
    f[0] += k.x; f[1] += k.y; f[2] += k.z; f[3] += k.w;
    f[4] += 0.5f*k.x*k.x; f[5] += k.x*k.y; f[6]  += k.x*k.z; f[7]  += k.x*k.w;
    f[8] += 0.5f*k.y*k.y; f[9] += k.y*k.z; f[10] += k.y*k.w;
    f[11] += 0.5f*k.z*k.z; f[12] += k.z*k.w; f[13] += 0.5f*k.w*k.w;
  }
#pragma unroll
  for (int m = 1; m < 64; m <<= 1) {
#pragma unroll
    for (int i = 0; i < 14; ++i) f[i] += __shfl_xor(f[i], m, 64);
  }
  if ((tid & 63) == 0) {
    float* SM = ws + OFF_SM + n*16;
#pragma unroll
    for (int i = 0; i < 14; ++i) atomicAdd(&SM[i], f[i]);
  }
}

// chunk W-moments (fused D): per pixel j compute D_j via Taylor-2, w = v/D, accumulate
// WM[n][c*15 + {M0, M1(4), M2'(10, diag half)}] = sum_j w_jc * {1, q, q⊗q}.  grid (4, 18) x 256
__global__ __launch_bounds__(256, 4) void k_cmom(float* __restrict__ ws)
{
  const int n = blockIdx.y;
  const int tid = threadIdx.x;
  const size_t base = (size_t)n*NPIX + blockIdx.x*1024;
  const float4* qc = reinterpret_cast<const float4*>(ws + OFF_QC) + base;
  const float4* vc = reinterpret_cast<const float4*>(ws + OFF_VC) + base;
  const float* SM = ws + OFF_SM + n*16;
  const float s10 = SM[0], s11 = SM[1], s12 = SM[2], s13 = SM[3];
  float s2[10];
#pragma unroll
  for (int i = 0; i < 10; ++i) s2[i] = SM[4+i];
  float mom[60];
#pragma unroll
  for (int i = 0; i < 60; ++i) mom[i] = 0.f;
#pragma unroll
  for (int s = 0; s < 4; ++s) {
    float4 q = qc[s*256 + tid];
    float4 v = vc[s*256 + tid];
    float P[10];  // plain q-products
    P[0] = q.x*q.x; P[1] = q.x*q.y; P[2] = q.x*q.z; P[3] = q.x*q.w;
    P[4] = q.y*q.y; P[5] = q.y*q.z; P[6] = q.y*q.w;
    P[7] = q.z*q.z; P[8] = q.z*q.w; P[9] = q.w*q.w;
    // D = sum_i e^{q.k_i} ~= N + q.S1 + sum S2'[ab] * plainP(q)
    float D = 4096.0f + s10*q.x + s11*q.y + s12*q.z + s13*q.w;
#pragma unroll
    for (int i = 0; i < 10; ++i) D += s2[i]*P[i];
    const float inv = 1.0f / D;
    const float wc[4] = { v.x*inv, v.y*inv, v.z*inv, v.w*inv };
    float F[15];  // coef-folded features for M accumulation
    F[0] = 1.f; F[1] = q.x; F[2] = q.y; F[3] = q.z; F[4] = q.w;
    F[5]  = 0.5f*P[0]; F[6]  = P[1]; F[7]  = P[2]; F[8] = P[3];
    F[9]  = 0.5f*P[4]; F[10] = P[5]; F[11] = P[6];
    F[12] = 0.5f*P[7]; F[13] = P[8]; F[14] = 0.5f*P[9];
#pragma unroll
    for (int c = 0; c < 4; ++c) {
#pragma unroll
      for (int i = 0; i < 15; ++i) mom[c*15 + i] += wc[c]*F[i];
    }
  }
#pragma unroll
  for (int m = 1; m < 64; m <<= 1) {
#pragma unroll
    for (int i = 0; i < 60; ++i) mom[i] += __shfl_xor(mom[i], m, 64);
  }
  if ((tid & 63) == 0) {
    float* WM = ws + OFF_WM + n*64;
#pragma unroll
    for (int i = 0; i < 60; ++i) atomicAdd(&WM[i], mom[i]);
  }
}

// global pass A (MFMA): D[j] = sum_i exp2(S[j][i]).  grid (64, 16) x 256, i-strip 256
__global__ __launch_bounds__(256, 4) void k_mA(float* __restrict__ ws)
{
  const unsigned short* QB = reinterpret_cast<const unsigned short*>(ws + OFF_QB);
  const unsigned short* KB = reinterpret_cast<const unsigned short*>(ws + OFF_KB);
  const int w = threadIdx.x >> 6, l = threadIdx.x & 63;
  const int g = l >> 4, li = l & 15;
  const int j0 = blockIdx.x * 64 + w * 16;
  const int i0 = blockIdx.y * 256;
  short8v qa[3];
#pragma unroll
  for (int kk = 0; kk < 3; ++kk)
    qa[kk] = *reinterpret_cast<const short8v*>(QB + (j0 + li)*KPAD + kk*32 + 8*g);
  float ds0 = 0.f, ds1 = 0.f, ds2 = 0.f, ds3 = 0.f;
#pragma unroll 2
  for (int t = 0; t < 16; ++t) {
    const int i = i0 + t*16;
    f32x4 acc = {0.f, 0.f, 0.f, 0.f};
#pragma unroll
    for (int kk = 0; kk < 3; ++kk) {
      short8v kb = *reinterpret_cast<const short8v*>(KB + (i + li)*KPAD + kk*32 + 8*g);
      acc = MFMA(qa[kk], kb, acc);
    }
    ds0 += fexp2(acc[0]);
    ds1 += fexp2(acc[1]);
    ds2 += fexp2(acc[2]);
    ds3 += fexp2(acc[3]);
  }
#pragma unroll
  for (int m = 1; m < 16; m <<= 1) {
    ds0 += __shfl_xor(ds0, m, 64);
    ds1 += __shfl_xor(ds1, m, 64);
    ds2 += __shfl_xor(ds2, m, 64);
    ds3 += __shfl_xor(ds3, m, 64);
  }
  if (li == 0) {
    float* D = ws + OFF_DG;
    atomicAdd(&D[j0 + 4*g + 0], ds0);
    atomicAdd(&D[j0 + 4*g + 1], ds1);
    atomicAdd(&D[j0 + 4*g + 2], ds2);
    atomicAdd(&D[j0 + 4*g + 3], ds3);
  }
}

// global w: WB = bf16(VG/D).  grid (16) x 256
__global__ void k_wcompG(float* __restrict__ ws)
{
  const int j = blockIdx.x * blockDim.x + threadIdx.x; // 0..4095
  const float inv = 1.0f / ws[OFF_DG + j];
  unsigned short* WB = reinterpret_cast<unsigned short*>(ws + OFF_WB);
  const float* VG = ws + OFF_VG;
#pragma unroll
  for (int c = 0; c < NCH; ++c)
    WB[c*NPIX + j] = bf16r(VG[c*NPIX + j] * inv);
#pragma unroll
  for (int c = NCH; c < 80; ++c) WB[c*NPIX + j] = 0;
}

// global pass B (MFMA): OUT[c][i] += sum_j WB[c][j]*exp2(S[j][i]).
// grid (64, 16) x 256, j-strip 256; double-buffered per-wave E-tile.
__global__ __launch_bounds__(256, 4) void k_mB(float* __restrict__ ws)
{
  __shared__ unsigned int E_dw[2][4][16][36];
  const unsigned short* QB = reinterpret_cast<const unsigned short*>(ws + OFF_QB);
  const unsigned short* KB = reinterpret_cast<const unsigned short*>(ws + OFF_KB);
  const unsigned short* WB = reinterpret_cast<const unsigned short*>(ws + OFF_WB);
  const int w = threadIdx.x >> 6, l = threadIdx.x & 63;
  const int g = l >> 4, li = l & 15;
  const int iw = blockIdx.x * 64 + w * 16;
  const int jbase = blockIdx.y * 256;
  short8v kb[3];
#pragma unroll
  for (int kk = 0; kk < 3; ++kk)
    kb[kk] = *reinterpret_cast<const short8v*>(KB + (iw + li)*KPAD + kk*32 + 8*g);
  f32x4 accW[5];
#pragma unroll
  for (int m = 0; m < 5; ++m) accW[m] = (f32x4){0.f, 0.f, 0.f, 0.f};
#pragma unroll 2
  for (int t = 0; t < 8; ++t) {
    const int jb = jbase + t*32;
    unsigned int (*Em)[36] = E_dw[t & 1][w];
#pragma unroll
    for (int m = 0; m < 2; ++m) {
      f32x4 acc = {0.f, 0.f, 0.f, 0.f};
#pragma unroll
      for (int kk = 0; kk < 3; ++kk) {
        short8v qa = *reinterpret_cast<const short8v*>(QB + (jb + m*16 + li)*KPAD + kk*32 + 8*g);
        acc = MFMA(qa, kb[kk], acc);
      }
      Em[li][m*8 + 2*g    ] = bf16pair(fexp2(acc[0]), fexp2(acc[1]));
      Em[li][m*8 + 2*g + 1] = bf16pair(fexp2(acc[2]), fexp2(acc[3]));
    }
    short8v eb = *reinterpret_cast<const short8v*>(&Em[li][4*g]);
#pragma unroll
    for (int m = 0; m < 5; ++m) {
      short8v wa = *reinterpret_cast<const short8v*>(WB + (m*16 + li)*NPIX + jb + 8*g);
      accW[m] = MFMA(wa, eb, accW[m]);
    }
  }
  float* OG = ws + OFF_OUTG;
#pragma unroll
  for (int m = 0; m < 5; ++m) {
#pragma unroll
    for (int r = 0; r < 4; ++r) {
      const int c = m*16 + 4*g + r;
      if (c < NCH) atomicAdd(&OG[c*NPIX + iw + li], accW[m][r]);
    }
  }
}

// final: outC evaluated from moments; pooled = sum_c x*(outC + outG).  grid (288) x 256
// n = blockIdx.x>>4 (block-uniform -> scalar moment loads)
__global__ void k_final(const float* __restrict__ x, const float* __restrict__ ws,
                        float* __restrict__ out)
{
  const int n = blockIdx.x >> 4;
  const int p = ((blockIdx.x & 15) << 8) + threadIdx.x;
  const float4 k = reinterpret_cast<const float4*>(ws + OFF_KC)[(size_t)n*NPIX + p];
  const float* M = ws + OFF_WM + n*64;
  float P[10];
  P[0] = k.x*k.x; P[1] = k.x*k.y; P[2] = k.x*k.z; P[3] = k.x*k.w;
  P[4] = k.y*k.y; P[5] = k.y*k.z; P[6] = k.y*k.w;
  P[7] = k.z*k.z; P[8] = k.z*k.w; P[9] = k.w*k.w;
  const float* og = ws + OFF_OUTG + (size_t)n*4*NPIX + p;
  float s = 0.f;
#pragma unroll
  for (int c = 0; c < 4; ++c) {
    const float* mc = M + c*15;
    float oc = mc[0] + mc[1]*k.x + mc[2]*k.y + mc[3]*k.z + mc[4]*k.w;
#pragma unroll
    for (int i = 0; i < 10; ++i) oc += mc[5+i]*P[i];
    s += x[(4*n + c)*NPIX + p] * (oc + og[c*NPIX]);
  }
  out[n*NPIX + p] = s;
}

extern "C" void kernel_launch(void* const* d_in, const int* in_sizes, int n_in,
                              void* d_out, int out_size, void* d_ws, size_t ws_size,
                              hipStream_t stream)
{
  const float* x   = (const float*)d_in[0];
  const float* Wq  = (const float*)d_in[1];
  const float* bq  = (const float*)d_in[2];
  const float* Wk  = (const float*)d_in[3];
  const float* bk  = (const float*)d_in[4];
  const float* Wv  = (const float*)d_in[5];
  const float* bv  = (const float*)d_in[6];
  const float* WqG = (const float*)d_in[7];
  const float* bqG = (const float*)d_in[8];
  const float* WkG = (const float*)d_in[9];
  const float* bkG = (const float*)d_in[10];
  const float* WvG = (const float*)d_in[11];
  const float* bvG = (const float*)d_in[12];
  float* ws  = (float*)d_ws;
  float* out = (float*)d_out;

  if (ws_size < (size_t)WS_FLOATS * sizeof(float)) return; // need ~8.2 MB scratch

  // zero atomic accumulators: DG+OUTG (contiguous), SM+WM (contiguous)
  hipMemsetAsync(ws + OFF_DG, 0, (size_t)(4096 + NCH*NPIX) * sizeof(float), stream);
  hipMemsetAsync(ws + OFF_SM, 0, (size_t)(WS_FLOATS - OFF_SM) * sizeof(float), stream);

  hipLaunchKernelGGL(k_qkv, dim3(16, 24), dim3(256), 0, stream,
                     x, Wq, bq, Wk, bk, Wv, bv, WqG, bqG, WkG, bkG, WvG, bvG, ws);
  hipLaunchKernelGGL(k_kmom, dim3(4, 18), dim3(256), 0, stream, ws);
  hipLaunchKernelGGL(k_mA, dim3(64, 16), dim3(256), 0, stream, ws);
  hipLaunchKernelGGL(k_cmom, dim3(4, 18), dim3(256), 0, stream, ws);
  hipLaunchKernelGGL(k_wcompG, dim3(16), dim3(256), 0, stream, ws);
  hipLaunchKernelGGL(k_mB, dim3(64, 16), dim3(256), 0, stream, ws);
  hipLaunchKernelGGL(k_final, dim3(288), dim3(256), 0, stream, x, ws, out);
}

// Round 12
// 103.405 us; speedup vs baseline: 1.0371x; 1.0371x over previous
//
#include <hip/hip_runtime.h>

#define NPIX 4096
#define NCH 72
#define NCHUNK 18
#define KPAD 96

static constexpr float SCALE_LOG2E = 0.022542110013890054f; // (1/64)*log2(e)
static constexpr float SCALE_N = 0.015625f;                 // 1/64

// ws layout (float offsets)
#define OFF_QC 0          // [18][4096][4] f32 chunk q (dead after k_cmom -> OUTG partial 0)
#define OFF_KC 294912     // [18][4096][4] f32 chunk k (live until k_final)
#define OFF_VC 589824     // [18][4096][4] f32 chunk v (dead after k_cmom -> OUTG partial 1)
#define OFF_VG 884736     // [72][4096] f32 global v (dead after k_wcompG -> OUTG partial 2)
#define OFF_DG 1179648    // [4096] f32 (atomics; memset)
#define OFF_OUTG 1183744  // [72][4096] f32 (OUTG partial 3, direct-stored)
#define OFF_QB 1478656    // bf16 [4096][96] global q (scaled, zero-padded 72..95)
#define OFF_KB 1675264    // bf16 [4096][96] global k (zero-padded)
#define OFF_WB 1871872    // bf16 [80][4096] global v/D (rows 72..79 zero)
#define OFF_SM 2035712    // [18][16] chunk K-moments (atomics; memset)
#define OFF_WM 2036000    // [18][64] chunk W-moments (atomics; memset)
#define WS_FLOATS 2037152

typedef __attribute__((ext_vector_type(8))) short short8v;
typedef __attribute__((ext_vector_type(4))) float f32x4;

__device__ __forceinline__ float fexp2(float x) {
#if __has_builtin(__builtin_amdgcn_exp2f)
  return __builtin_amdgcn_exp2f(x);
#else
  return exp2f(x);
#endif
}

__device__ __forceinline__ unsigned short bf16r(float f) {
  unsigned int u = __float_as_uint(f);
  u = (u + 0x7FFFu + ((u >> 16) & 1u)) >> 16;
  return (unsigned short)u;
}
__device__ __forceinline__ unsigned int bf16pair(float lo, float hi) {
  return (unsigned int)bf16r(lo) | ((unsigned int)bf16r(hi) << 16);
}

__device__ __forceinline__ f32x4 MFMA(short8v a, short8v b, f32x4 c) {
  return __builtin_amdgcn_mfma_f32_16x16x32_bf16(a, b, c, 0, 0, 0);
}

__device__ __forceinline__ float dot4(float4 a, float4 b) {
  return a.x*b.x + a.y*b.y + a.z*b.z + a.w*b.w;
}

__device__ __forceinline__ float4 mix4(const float* __restrict__ W, const float* __restrict__ b,
                                       float x0, float x1, float x2, float x3, float sc)
{
  float4 r;
  r.x = (b[0] + W[0]*x0  + W[1]*x1  + W[2]*x2  + W[3]*x3)  * sc;
  r.y = (b[1] + W[4]*x0  + W[5]*x1  + W[6]*x2  + W[7]*x3)  * sc;
  r.z = (b[2] + W[8]*x0  + W[9]*x1  + W[10]*x2 + W[11]*x3) * sc;
  r.w = (b[3] + W[12]*x0 + W[13]*x1 + W[14]*x2 + W[15]*x3) * sc;
  return r;
}

// grid (16, 24) x 256. seg 0..5: chunk qkv (3 chunks each, f32). seg 6..23: global (mat m, group of 12)
__global__ __launch_bounds__(256, 3) void k_qkv(const float* __restrict__ x,
    const float* __restrict__ Wq, const float* __restrict__ bq,
    const float* __restrict__ Wk, const float* __restrict__ bk,
    const float* __restrict__ Wv, const float* __restrict__ bv,
    const float* __restrict__ WqG, const float* __restrict__ bqG,
    const float* __restrict__ WkG, const float* __restrict__ bkG,
    const float* __restrict__ WvG, const float* __restrict__ bvG,
    float* __restrict__ ws)
{
  const int p = blockIdx.x * blockDim.x + threadIdx.x;
  const int seg = blockIdx.y;
  if (seg < 6) {
    float4* qd = reinterpret_cast<float4*>(ws + OFF_QC);
    float4* kd = reinterpret_cast<float4*>(ws + OFF_KC);
    float4* vd = reinterpret_cast<float4*>(ws + OFF_VC);
    const int n0 = seg * 3;
#pragma unroll
    for (int dn = 0; dn < 3; ++dn) {
      const int n = n0 + dn;
      const float x0 = x[(4*n+0)*NPIX + p];
      const float x1 = x[(4*n+1)*NPIX + p];
      const float x2 = x[(4*n+2)*NPIX + p];
      const float x3 = x[(4*n+3)*NPIX + p];
      float4 q = mix4(Wq + n*16, bq + n*4, x0, x1, x2, x3, SCALE_N);
      float4 k = mix4(Wk + n*16, bk + n*4, x0, x1, x2, x3, 1.0f);
      float4 v = mix4(Wv + n*16, bv + n*4, x0, x1, x2, x3, 1.0f);
      qd[(size_t)n*NPIX + p] = q;
      kd[(size_t)n*NPIX + p] = k;
      vd[(size_t)n*NPIX + p] = v;
    }
  } else {
    const int m = (seg - 6) / 6;
    const int g6 = (seg - 6) % 6;
    const float* W = (m == 0) ? WqG : (m == 1) ? WkG : WvG;
    const float* b = (m == 0) ? bqG : (m == 1) ? bkG : bvG;
    float4 xv[18];
#pragma unroll
    for (int c = 0; c < 18; ++c) {
      float4 t;
      t.x = x[(4*c+0)*NPIX + p];
      t.y = x[(4*c+1)*NPIX + p];
      t.z = x[(4*c+2)*NPIX + p];
      t.w = x[(4*c+3)*NPIX + p];
      xv[c] = t;
    }
    const int ob = g6 * 12;
    if (m == 2) {
      float* dst = ws + OFF_VG; // [72][4096]
      for (int o = ob; o < ob + 12; ++o) {
        float acc = b[o];
        const float4* wrow = reinterpret_cast<const float4*>(W + o*NCH);
#pragma unroll
        for (int c = 0; c < 18; ++c) acc += dot4(wrow[c], xv[c]);
        dst[o*NPIX + p] = acc;
      }
    } else {
      unsigned short* dst = reinterpret_cast<unsigned short*>(ws + ((m == 0) ? OFF_QB : OFF_KB));
      const float sc = (m == 0) ? SCALE_LOG2E : 1.0f;
      for (int o = ob; o < ob + 12; ++o) {
        float acc = b[o];
        const float4* wrow = reinterpret_cast<const float4*>(W + o*NCH);
#pragma unroll
        for (int c = 0; c < 18; ++c) acc += dot4(wrow[c], xv[c]);
        dst[p*KPAD + o] = bf16r(acc * sc);
      }
      if (g6 == 5) {
#pragma unroll
        for (int o = NCH; o < KPAD; ++o) dst[p*KPAD + o] = 0;
      }
    }
  }
}

// chunk K-moments: SM[n] = [S1(4), S2'(10, diag half)] summed over all i.  grid (4, 18) x 256
__global__ __launch_bounds__(256, 4) void k_kmom(float* __restrict__ ws)
{
  const int n = blockIdx.y;
  const int tid = threadIdx.x;
  const float4* kc = reinterpret_cast<const float4*>(ws + OFF_KC) + (size_t)n*NPIX + blockIdx.x*1024;
  float f[14];
#pragma unroll
  for (int i = 0; i < 14; ++i) f[i] = 0.f;
#pragma unroll
  for (int s = 0; s < 4; ++s) {
    float4 k = kc[s*256 + tid];
    f[0] += k.x; f[1] += k.y; f[2] += k.z; f[3] += k.w;
    f[4] += 0.5f*k.x*k.x; f[5] += k.x*k.y; f[6]  += k.x*k.z; f[7]  += k.x*k.w;
    f[8] += 0.5f*k.y*k.y; f[9] += k.y*k.z; f[10] += k.y*k.w;
    f[11] += 0.5f*k.z*k.z; f[12] += k.z*k.w; f[13] += 0.5f*k.w*k.w;
  }
#pragma unroll
  for (int m = 1; m < 64; m <<= 1) {
#pragma unroll
    for (int i = 0; i < 14; ++i) f[i] += __shfl_xor(f[i], m, 64);
  }
  if ((tid & 63) == 0) {
    float* SM = ws + OFF_SM + n*16;
#pragma unroll
    for (int i = 0; i < 14; ++i) atomicAdd(&SM[i], f[i]);
  }
}

// chunk W-moments (fused D): D_j via Taylor-2, w = v/D, accumulate moments.  grid (4, 18) x 256
__global__ __launch_bounds__(256, 4) void k_cmom(float* __restrict__ ws)
{
  const int n = blockIdx.y;
  const int tid = threadIdx.x;
  const size_t base = (size_t)n*NPIX + blockIdx.x*1024;
  const float4* qc = reinterpret_cast<const float4*>(ws + OFF_QC) + base;
  const float4* vc = reinterpret_cast<const float4*>(ws + OFF_VC) + base;
  const float* SM = ws + OFF_SM + n*16;
  const float s10 = SM[0], s11 = SM[1], s12 = SM[2], s13 = SM[3];
  float s2[10];
#pragma unroll
  for (int i = 0; i < 10; ++i) s2[i] = SM[4+i];
  float mom[60];
#pragma unroll
  for (int i = 0; i < 60; ++i) mom[i] = 0.f;
#pragma unroll
  for (int s = 0; s < 4; ++s) {
    float4 q = qc[s*256 + tid];
    float4 v = vc[s*256 + tid];
    float P[10];  // plain q-products
    P[0] = q.x*q.x; P[1] = q.x*q.y; P[2] = q.x*q.z; P[3] = q.x*q.w;
    P[4] = q.y*q.y; P[5] = q.y*q.z; P[6] = q.y*q.w;
    P[7] = q.z*q.z; P[8] = q.z*q.w; P[9] = q.w*q.w;
    float D = 4096.0f + s10*q.x + s11*q.y + s12*q.z + s13*q.w;
#pragma unroll
    for (int i = 0; i < 10; ++i) D += s2[i]*P[i];
    const float inv = 1.0f / D;
    const float wc[4] = { v.x*inv, v.y*inv, v.z*inv, v.w*inv };
    float F[15];
    F[0] = 1.f; F[1] = q.x; F[2] = q.y; F[3] = q.z; F[4] = q.w;
    F[5]  = 0.5f*P[0]; F[6]  = P[1]; F[7]  = P[2]; F[8] = P[3];
    F[9]  = 0.5f*P[4]; F[10] = P[5]; F[11] = P[6];
    F[12] = 0.5f*P[7]; F[13] = P[8]; F[14] = 0.5f*P[9];
#pragma unroll
    for (int c = 0; c < 4; ++c) {
#pragma unroll
      for (int i = 0; i < 15; ++i) mom[c*15 + i] += wc[c]*F[i];
    }
  }
#pragma unroll
  for (int m = 1; m < 64; m <<= 1) {
#pragma unroll
    for (int i = 0; i < 60; ++i) mom[i] += __shfl_xor(mom[i], m, 64);
  }
  if ((tid & 63) == 0) {
    float* WM = ws + OFF_WM + n*64;
#pragma unroll
    for (int i = 0; i < 60; ++i) atomicAdd(&WM[i], mom[i]);
  }
}

// global pass A (MFMA): D[j] = sum_i exp2(S[j][i]).  grid (64, 16) x 256, i-strip 256
__global__ __launch_bounds__(256, 4) void k_mA(float* __restrict__ ws)
{
  const unsigned short* QB = reinterpret_cast<const unsigned short*>(ws + OFF_QB);
  const unsigned short* KB = reinterpret_cast<const unsigned short*>(ws + OFF_KB);
  const int w = threadIdx.x >> 6, l = threadIdx.x & 63;
  const int g = l >> 4, li = l & 15;
  const int j0 = blockIdx.x * 64 + w * 16;
  const int i0 = blockIdx.y * 256;
  short8v qa[3];
#pragma unroll
  for (int kk = 0; kk < 3; ++kk)
    qa[kk] = *reinterpret_cast<const short8v*>(QB + (j0 + li)*KPAD + kk*32 + 8*g);
  float ds0 = 0.f, ds1 = 0.f, ds2 = 0.f, ds3 = 0.f;
#pragma unroll 2
  for (int t = 0; t < 16; ++t) {
    const int i = i0 + t*16;
    f32x4 acc = {0.f, 0.f, 0.f, 0.f};
#pragma unroll
    for (int kk = 0; kk < 3; ++kk) {
      short8v kb = *reinterpret_cast<const short8v*>(KB + (i + li)*KPAD + kk*32 + 8*g);
      acc = MFMA(qa[kk], kb, acc);
    }
    ds0 += fexp2(acc[0]);
    ds1 += fexp2(acc[1]);
    ds2 += fexp2(acc[2]);
    ds3 += fexp2(acc[3]);
  }
#pragma unroll
  for (int m = 1; m < 16; m <<= 1) {
    ds0 += __shfl_xor(ds0, m, 64);
    ds1 += __shfl_xor(ds1, m, 64);
    ds2 += __shfl_xor(ds2, m, 64);
    ds3 += __shfl_xor(ds3, m, 64);
  }
  if (li == 0) {
    float* D = ws + OFF_DG;
    atomicAdd(&D[j0 + 4*g + 0], ds0);
    atomicAdd(&D[j0 + 4*g + 1], ds1);
    atomicAdd(&D[j0 + 4*g + 2], ds2);
    atomicAdd(&D[j0 + 4*g + 3], ds3);
  }
}

// global w: WB = bf16(VG/D).  grid (16) x 256
__global__ void k_wcompG(float* __restrict__ ws)
{
  const int j = blockIdx.x * blockDim.x + threadIdx.x; // 0..4095
  const float inv = 1.0f / ws[OFF_DG + j];
  unsigned short* WB = reinterpret_cast<unsigned short*>(ws + OFF_WB);
  const float* VG = ws + OFF_VG;
#pragma unroll
  for (int c = 0; c < NCH; ++c)
    WB[c*NPIX + j] = bf16r(VG[c*NPIX + j] * inv);
#pragma unroll
  for (int c = NCH; c < 80; ++c) WB[c*NPIX + j] = 0;
}

// global pass B (MFMA): OUTGP[s][c][i] = sum_{j in strip s} WB[c][j]*exp2(S[j][i]).
// grid (256, 4) x 256: block = 16 i, strip of 1024 j; 4 waves split the strip (256 j each).
// LDS tree-combine across waves, wave 0 direct-stores the 72x16 f32 tile.  NO atomics.
__global__ __launch_bounds__(256, 4) void k_mB(float* __restrict__ ws)
{
  __shared__ unsigned int E_dw[2][4][16][36];
  __shared__ f32x4 red[3][64][5];
  const unsigned short* QB = reinterpret_cast<const unsigned short*>(ws + OFF_QB);
  const unsigned short* KB = reinterpret_cast<const unsigned short*>(ws + OFF_KB);
  const unsigned short* WB = reinterpret_cast<const unsigned short*>(ws + OFF_WB);
  const int w = threadIdx.x >> 6, l = threadIdx.x & 63;
  const int g = l >> 4, li = l & 15;
  const int i0 = blockIdx.x * 16;
  const int s = blockIdx.y;
  const int jbase = s * 1024 + w * 256;
  short8v kb[3];
#pragma unroll
  for (int kk = 0; kk < 3; ++kk)
    kb[kk] = *reinterpret_cast<const short8v*>(KB + (i0 + li)*KPAD + kk*32 + 8*g);
  f32x4 accW[5];
#pragma unroll
  for (int m = 0; m < 5; ++m) accW[m] = (f32x4){0.f, 0.f, 0.f, 0.f};
#pragma unroll 2
  for (int t = 0; t < 8; ++t) {
    const int jb = jbase + t*32;
    unsigned int (*Em)[36] = E_dw[t & 1][w];
#pragma unroll
    for (int m = 0; m < 2; ++m) {
      f32x4 acc = {0.f, 0.f, 0.f, 0.f};
#pragma unroll
      for (int kk = 0; kk < 3; ++kk) {
        short8v qa = *reinterpret_cast<const short8v*>(QB + (jb + m*16 + li)*KPAD + kk*32 + 8*g);
        acc = MFMA(qa, kb[kk], acc);
      }
      Em[li][m*8 + 2*g    ] = bf16pair(fexp2(acc[0]), fexp2(acc[1]));
      Em[li][m*8 + 2*g + 1] = bf16pair(fexp2(acc[2]), fexp2(acc[3]));
    }
    short8v eb = *reinterpret_cast<const short8v*>(&Em[li][4*g]);
#pragma unroll
    for (int m = 0; m < 5; ++m) {
      short8v wa = *reinterpret_cast<const short8v*>(WB + (m*16 + li)*NPIX + jb + 8*g);
      accW[m] = MFMA(wa, eb, accW[m]);
    }
  }
  // combine the 4 waves' accumulators (they cover disjoint j) in LDS
  if (w > 0) {
#pragma unroll
    for (int m = 0; m < 5; ++m) red[w-1][l][m] = accW[m];
  }
  __syncthreads();
  if (w == 0) {
#pragma unroll
    for (int o = 0; o < 3; ++o)
#pragma unroll
      for (int m = 0; m < 5; ++m) accW[m] += red[o][l][m];
    const int pbase[4] = { OFF_QC, OFF_VC, OFF_VG, OFF_OUTG };
    float* OP = ws + pbase[s];
#pragma unroll
    for (int m = 0; m < 5; ++m) {
#pragma unroll
      for (int r = 0; r < 4; ++r) {
        const int c = m*16 + 4*g + r;
        if (c < NCH) OP[(size_t)c*NPIX + i0 + li] = accW[m][r];
      }
    }
  }
}

// final: outC from moments; pooled = sum_c x*(outC + sum_s OUTGP[s]).  grid (288) x 256
__global__ void k_final(const float* __restrict__ x, const float* __restrict__ ws,
                        float* __restrict__ out)
{
  const int n = blockIdx.x >> 4;
  const int p = ((blockIdx.x & 15) << 8) + threadIdx.x;
  const float4 k = reinterpret_cast<const float4*>(ws + OFF_KC)[(size_t)n*NPIX + p];
  const float* M = ws + OFF_WM + n*64;
  float P[10];
  P[0] = k.x*k.x; P[1] = k.x*k.y; P[2] = k.x*k.z; P[3] = k.x*k.w;
  P[4] = k.y*k.y; P[5] = k.y*k.z; P[6] = k.y*k.w;
  P[7] = k.z*k.z; P[8] = k.z*k.w; P[9] = k.w*k.w;
  float s = 0.f;
#pragma unroll
  for (int c = 0; c < 4; ++c) {
    const float* mc = M + c*15;
    float oc = mc[0] + mc[1]*k.x + mc[2]*k.y + mc[3]*k.z + mc[4]*k.w;
#pragma unroll
    for (int i = 0; i < 10; ++i) oc += mc[5+i]*P[i];
    const size_t off = (size_t)(4*n + c)*NPIX + p;
    const float og = ws[OFF_QC + off] + ws[OFF_VC + off]
                   + ws[OFF_VG + off] + ws[OFF_OUTG + off];
    s += x[off] * (oc + og);
  }
  out[n*NPIX + p] = s;
}

extern "C" void kernel_launch(void* const* d_in, const int* in_sizes, int n_in,
                              void* d_out, int out_size, void* d_ws, size_t ws_size,
                              hipStream_t stream)
{
  const float* x   = (const float*)d_in[0];
  const float* Wq  = (const float*)d_in[1];
  const float* bq  = (const float*)d_in[2];
  const float* Wk  = (const float*)d_in[3];
  const float* bk  = (const float*)d_in[4];
  const float* Wv  = (const float*)d_in[5];
  const float* bv  = (const float*)d_in[6];
  const float* WqG = (const float*)d_in[7];
  const float* bqG = (const float*)d_in[8];
  const float* WkG = (const float*)d_in[9];
  const float* bkG = (const float*)d_in[10];
  const float* WvG = (const float*)d_in[11];
  const float* bvG = (const float*)d_in[12];
  float* ws  = (float*)d_ws;
  float* out = (float*)d_out;

  if (ws_size < (size_t)WS_FLOATS * sizeof(float)) return; // need ~8.2 MB scratch

  // zero atomic accumulators: DG, SM+WM
  hipMemsetAsync(ws + OFF_DG, 0, (size_t)4096 * sizeof(float), stream);
  hipMemsetAsync(ws + OFF_SM, 0, (size_t)(WS_FLOATS - OFF_SM) * sizeof(float), stream);

  hipLaunchKernelGGL(k_qkv, dim3(16, 24), dim3(256), 0, stream,
                     x, Wq, bq, Wk, bk, Wv, bv, WqG, bqG, WkG, bkG, WvG, bvG, ws);
  hipLaunchKernelGGL(k_kmom, dim3(4, 18), dim3(256), 0, stream, ws);
  hipLaunchKernelGGL(k_mA, dim3(64, 16), dim3(256), 0, stream, ws);
  hipLaunchKernelGGL(k_cmom, dim3(4, 18), dim3(256), 0, stream, ws);
  hipLaunchKernelGGL(k_wcompG, dim3(16), dim3(256), 0, stream, ws);
  hipLaunchKernelGGL(k_mB, dim3(256, 4), dim3(256), 0, stream, ws);
  hipLaunchKernelGGL(k_final, dim3(288), dim3(256), 0, stream, x, ws, out);
}

// Round 13
// 94.395 us; speedup vs baseline: 1.1361x; 1.0954x over previous
//
#include <hip/hip_runtime.h>

#define NPIX 4096
#define NCH 72
#define NCHUNK 18
#define KPAD 96

static constexpr float SCALE_LOG2E = 0.022542110013890054f; // (1/64)*log2(e)
static constexpr float SCALE_N = 0.015625f;                 // 1/64

// ws layout (float offsets)
#define OFF_QC 0          // [18][4096][4] f32 chunk q (dead after k_cmom -> OUTG partial 0)
#define OFF_KC 294912     // [18][4096][4] f32 chunk k (live until k_final)
#define OFF_VC 589824     // [18][4096][4] f32 chunk v (dead after k_cmom -> OUTG partial 1)
#define OFF_VG 884736     // [72][4096] f32 global v (dead after k_wcompG -> OUTG partial 2)
#define OFF_DG 1179648    // [4096] f32 (atomics; zeroed by k_qkv seg0)
#define OFF_OUTG 1183744  // [72][4096] f32 (OUTG partial 3, direct-stored)
#define OFF_QB 1478656    // bf16 [4096][96] global q (scaled, zero-padded 72..95)
#define OFF_KB 1675264    // bf16 [4096][96] global k (zero-padded)
#define OFF_WB 1871872    // bf16 [80][4096] global v/D (rows 72..79 zero)
#define OFF_SM 2035712    // [18][16] chunk K-moments (atomics; zeroed by k_qkv seg0/blk0)
#define OFF_WM 2036000    // [18][64] chunk W-moments (atomics; zeroed by k_qkv seg0/blk0)
#define WS_FLOATS 2037152

typedef __attribute__((ext_vector_type(8))) short short8v;
typedef __attribute__((ext_vector_type(4))) float f32x4;

__device__ __forceinline__ float fexp2(float x) {
#if __has_builtin(__builtin_amdgcn_exp2f)
  return __builtin_amdgcn_exp2f(x);
#else
  return exp2f(x);
#endif
}

__device__ __forceinline__ unsigned short bf16r(float f) {
  unsigned int u = __float_as_uint(f);
  u = (u + 0x7FFFu + ((u >> 16) & 1u)) >> 16;
  return (unsigned short)u;
}
__device__ __forceinline__ unsigned int bf16pair(float lo, float hi) {
  return (unsigned int)bf16r(lo) | ((unsigned int)bf16r(hi) << 16);
}

__device__ __forceinline__ f32x4 MFMA(short8v a, short8v b, f32x4 c) {
  return __builtin_amdgcn_mfma_f32_16x16x32_bf16(a, b, c, 0, 0, 0);
}

__device__ __forceinline__ float dot4(float4 a, float4 b) {
  return a.x*b.x + a.y*b.y + a.z*b.z + a.w*b.w;
}

__device__ __forceinline__ float4 mix4(const float* __restrict__ W, const float* __restrict__ b,
                                       float x0, float x1, float x2, float x3, float sc)
{
  float4 r;
  r.x = (b[0] + W[0]*x0  + W[1]*x1  + W[2]*x2  + W[3]*x3)  * sc;
  r.y = (b[1] + W[4]*x0  + W[5]*x1  + W[6]*x2  + W[7]*x3)  * sc;
  r.z = (b[2] + W[8]*x0  + W[9]*x1  + W[10]*x2 + W[11]*x3) * sc;
  r.w = (b[3] + W[12]*x0 + W[13]*x1 + W[14]*x2 + W[15]*x3) * sc;
  return r;
}

// grid (16, 24) x 256. seg 0..5: chunk qkv (3 chunks each, f32) + accumulator zeroing (seg 0).
// seg 6..23: global (mat m, group of 12)
__global__ __launch_bounds__(256, 3) void k_qkv(const float* __restrict__ x,
    const float* __restrict__ Wq, const float* __restrict__ bq,
    const float* __restrict__ Wk, const float* __restrict__ bk,
    const float* __restrict__ Wv, const float* __restrict__ bv,
    const float* __restrict__ WqG, const float* __restrict__ bqG,
    const float* __restrict__ WkG, const float* __restrict__ bkG,
    const float* __restrict__ WvG, const float* __restrict__ bvG,
    float* __restrict__ ws)
{
  const int p = blockIdx.x * blockDim.x + threadIdx.x;
  const int seg = blockIdx.y;
  if (seg < 6) {
    if (seg == 0) {
      ws[OFF_DG + p] = 0.f;                       // consumed by k_mA (2 launches later)
      if (blockIdx.x == 0) {
        for (int i = threadIdx.x; i < WS_FLOATS - OFF_SM; i += 256)
          ws[OFF_SM + i] = 0.f;                   // SM+WM, consumed by k_kmom/k_cmom
      }
    }
    float4* qd = reinterpret_cast<float4*>(ws + OFF_QC);
    float4* kd = reinterpret_cast<float4*>(ws + OFF_KC);
    float4* vd = reinterpret_cast<float4*>(ws + OFF_VC);
    const int n0 = seg * 3;
#pragma unroll
    for (int dn = 0; dn < 3; ++dn) {
      const int n = n0 + dn;
      const float x0 = x[(4*n+0)*NPIX + p];
      const float x1 = x[(4*n+1)*NPIX + p];
      const float x2 = x[(4*n+2)*NPIX + p];
      const float x3 = x[(4*n+3)*NPIX + p];
      float4 q = mix4(Wq + n*16, bq + n*4, x0, x1, x2, x3, SCALE_N);
      float4 k = mix4(Wk + n*16, bk + n*4, x0, x1, x2, x3, 1.0f);
      float4 v = mix4(Wv + n*16, bv + n*4, x0, x1, x2, x3, 1.0f);
      qd[(size_t)n*NPIX + p] = q;
      kd[(size_t)n*NPIX + p] = k;
      vd[(size_t)n*NPIX + p] = v;
    }
  } else {
    const int m = (seg - 6) / 6;
    const int g6 = (seg - 6) % 6;
    const float* W = (m == 0) ? WqG : (m == 1) ? WkG : WvG;
    const float* b = (m == 0) ? bqG : (m == 1) ? bkG : bvG;
    float4 xv[18];
#pragma unroll
    for (int c = 0; c < 18; ++c) {
      float4 t;
      t.x = x[(4*c+0)*NPIX + p];
      t.y = x[(4*c+1)*NPIX + p];
      t.z = x[(4*c+2)*NPIX + p];
      t.w = x[(4*c+3)*NPIX + p];
      xv[c] = t;
    }
    const int ob = g6 * 12;
    if (m == 2) {
      float* dst = ws + OFF_VG; // [72][4096]
      for (int o = ob; o < ob + 12; ++o) {
        float acc = b[o];
        const float4* wrow = reinterpret_cast<const float4*>(W + o*NCH);
#pragma unroll
        for (int c = 0; c < 18; ++c) acc += dot4(wrow[c], xv[c]);
        dst[o*NPIX + p] = acc;
      }
    } else {
      unsigned short* dst = reinterpret_cast<unsigned short*>(ws + ((m == 0) ? OFF_QB : OFF_KB));
      const float sc = (m == 0) ? SCALE_LOG2E : 1.0f;
      for (int o = ob; o < ob + 12; ++o) {
        float acc = b[o];
        const float4* wrow = reinterpret_cast<const float4*>(W + o*NCH);
#pragma unroll
        for (int c = 0; c < 18; ++c) acc += dot4(wrow[c], xv[c]);
        dst[p*KPAD + o] = bf16r(acc * sc);
      }
      if (g6 == 5) {
#pragma unroll
        for (int o = NCH; o < KPAD; ++o) dst[p*KPAD + o] = 0;
      }
    }
  }
}

// chunk K-moments: SM[n] = [S1(4), S2'(10, diag half)] summed over all i.  grid (4, 18) x 256
__global__ __launch_bounds__(256, 4) void k_kmom(float* __restrict__ ws)
{
  const int n = blockIdx.y;
  const int tid = threadIdx.x;
  const float4* kc = reinterpret_cast<const float4*>(ws + OFF_KC) + (size_t)n*NPIX + blockIdx.x*1024;
  float f[14];
#pragma unroll
  for (int i = 0; i < 14; ++i) f[i] = 0.f;
#pragma unroll
  for (int s = 0; s < 4; ++s) {
    float4 k = kc[s*256 + tid];
    f[0] += k.x; f[1] += k.y; f[2] += k.z; f[3] += k.w;
    f[4] += 0.5f*k.x*k.x; f[5] += k.x*k.y; f[6]  += k.x*k.z; f[7]  += k.x*k.w;
    f[8] += 0.5f*k.y*k.y; f[9] += k.y*k.z; f[10] += k.y*k.w;
    f[11] += 0.5f*k.z*k.z; f[12] += k.z*k.w; f[13] += 0.5f*k.w*k.w;
  }
#pragma unroll
  for (int m = 1; m < 64; m <<= 1) {
#pragma unroll
    for (int i = 0; i < 14; ++i) f[i] += __shfl_xor(f[i], m, 64);
  }
  if ((tid & 63) == 0) {
    float* SM = ws + OFF_SM + n*16;
#pragma unroll
    for (int i = 0; i < 14; ++i) atomicAdd(&SM[i], f[i]);
  }
}

// chunk W-moments (fused D): D_j via Taylor-2, w = v/D, accumulate moments.  grid (4, 18) x 256
__global__ __launch_bounds__(256, 4) void k_cmom(float* __restrict__ ws)
{
  const int n = blockIdx.y;
  const int tid = threadIdx.x;
  const size_t base = (size_t)n*NPIX + blockIdx.x*1024;
  const float4* qc = reinterpret_cast<const float4*>(ws + OFF_QC) + base;
  const float4* vc = reinterpret_cast<const float4*>(ws + OFF_VC) + base;
  const float* SM = ws + OFF_SM + n*16;
  const float s10 = SM[0], s11 = SM[1], s12 = SM[2], s13 = SM[3];
  float s2[10];
#pragma unroll
  for (int i = 0; i < 10; ++i) s2[i] = SM[4+i];
  float mom[60];
#pragma unroll
  for (int i = 0; i < 60; ++i) mom[i] = 0.f;
#pragma unroll
  for (int s = 0; s < 4; ++s) {
    float4 q = qc[s*256 + tid];
    float4 v = vc[s*256 + tid];
    float P[10];  // plain q-products
    P[0] = q.x*q.x; P[1] = q.x*q.y; P[2] = q.x*q.z; P[3] = q.x*q.w;
    P[4] = q.y*q.y; P[5] = q.y*q.z; P[6] = q.y*q.w;
    P[7] = q.z*q.z; P[8] = q.z*q.w; P[9] = q.w*q.w;
    float D = 4096.0f + s10*q.x + s11*q.y + s12*q.z + s13*q.w;
#pragma unroll
    for (int i = 0; i < 10; ++i) D += s2[i]*P[i];
    const float inv = 1.0f / D;
    const float wc[4] = { v.x*inv, v.y*inv, v.z*inv, v.w*inv };
    float F[15];
    F[0] = 1.f; F[1] = q.x; F[2] = q.y; F[3] = q.z; F[4] = q.w;
    F[5]  = 0.5f*P[0]; F[6]  = P[1]; F[7]  = P[2]; F[8] = P[3];
    F[9]  = 0.5f*P[4]; F[10] = P[5]; F[11] = P[6];
    F[12] = 0.5f*P[7]; F[13] = P[8]; F[14] = 0.5f*P[9];
#pragma unroll
    for (int c = 0; c < 4; ++c) {
#pragma unroll
      for (int i = 0; i < 15; ++i) mom[c*15 + i] += wc[c]*F[i];
    }
  }
#pragma unroll
  for (int m = 1; m < 64; m <<= 1) {
#pragma unroll
    for (int i = 0; i < 60; ++i) mom[i] += __shfl_xor(mom[i], m, 64);
  }
  if ((tid & 63) == 0) {
    float* WM = ws + OFF_WM + n*64;
#pragma unroll
    for (int i = 0; i < 60; ++i) atomicAdd(&WM[i], mom[i]);
  }
}

// global pass A (MFMA): D[j] = sum_i exp2(S[j][i]).  grid (64, 16) x 256, i-strip 256
__global__ __launch_bounds__(256, 4) void k_mA(float* __restrict__ ws)
{
  const unsigned short* QB = reinterpret_cast<const unsigned short*>(ws + OFF_QB);
  const unsigned short* KB = reinterpret_cast<const unsigned short*>(ws + OFF_KB);
  const int w = threadIdx.x >> 6, l = threadIdx.x & 63;
  const int g = l >> 4, li = l & 15;
  const int j0 = blockIdx.x * 64 + w * 16;
  const int i0 = blockIdx.y * 256;
  short8v qa[3];
#pragma unroll
  for (int kk = 0; kk < 3; ++kk)
    qa[kk] = *reinterpret_cast<const short8v*>(QB + (j0 + li)*KPAD + kk*32 + 8*g);
  float ds0 = 0.f, ds1 = 0.f, ds2 = 0.f, ds3 = 0.f;
#pragma unroll 2
  for (int t = 0; t < 16; ++t) {
    const int i = i0 + t*16;
    f32x4 acc = {0.f, 0.f, 0.f, 0.f};
#pragma unroll
    for (int kk = 0; kk < 3; ++kk) {
      short8v kb = *reinterpret_cast<const short8v*>(KB + (i + li)*KPAD + kk*32 + 8*g);
      acc = MFMA(qa[kk], kb, acc);
    }
    ds0 += fexp2(acc[0]);
    ds1 += fexp2(acc[1]);
    ds2 += fexp2(acc[2]);
    ds3 += fexp2(acc[3]);
  }
#pragma unroll
  for (int m = 1; m < 16; m <<= 1) {
    ds0 += __shfl_xor(ds0, m, 64);
    ds1 += __shfl_xor(ds1, m, 64);
    ds2 += __shfl_xor(ds2, m, 64);
    ds3 += __shfl_xor(ds3, m, 64);
  }
  if (li == 0) {
    float* D = ws + OFF_DG;
    atomicAdd(&D[j0 + 4*g + 0], ds0);
    atomicAdd(&D[j0 + 4*g + 1], ds1);
    atomicAdd(&D[j0 + 4*g + 2], ds2);
    atomicAdd(&D[j0 + 4*g + 3], ds3);
  }
}

// global w: WB = bf16(VG/D).  grid (16) x 256
__global__ void k_wcompG(float* __restrict__ ws)
{
  const int j = blockIdx.x * blockDim.x + threadIdx.x; // 0..4095
  const float inv = 1.0f / ws[OFF_DG + j];
  unsigned short* WB = reinterpret_cast<unsigned short*>(ws + OFF_WB);
  const float* VG = ws + OFF_VG;
#pragma unroll
  for (int c = 0; c < NCH; ++c)
    WB[c*NPIX + j] = bf16r(VG[c*NPIX + j] * inv);
#pragma unroll
  for (int c = NCH; c < 80; ++c) WB[c*NPIX + j] = 0;
}

// global pass B (MFMA): OUTGP[s][c][i] = sum_{j in strip s} WB[c][j]*exp2(S[j][i]).
// grid (256, 4) x 256: block = 16 i, strip of 1024 j; 4 waves split the strip (256 j each).
// LDS tree-combine across waves, wave 0 direct-stores the 72x16 f32 tile.  NO atomics.
__global__ __launch_bounds__(256, 4) void k_mB(float* __restrict__ ws)
{
  __shared__ unsigned int E_dw[2][4][16][36];
  __shared__ f32x4 red[3][64][5];
  const unsigned short* QB = reinterpret_cast<const unsigned short*>(ws + OFF_QB);
  const unsigned short* KB = reinterpret_cast<const unsigned short*>(ws + OFF_KB);
  const unsigned short* WB = reinterpret_cast<const unsigned short*>(ws + OFF_WB);
  const int w = threadIdx.x >> 6, l = threadIdx.x & 63;
  const int g = l >> 4, li = l & 15;
  const int i0 = blockIdx.x * 16;
  const int s = blockIdx.y;
  const int jbase = s * 1024 + w * 256;
  short8v kb[3];
#pragma unroll
  for (int kk = 0; kk < 3; ++kk)
    kb[kk] = *reinterpret_cast<const short8v*>(KB + (i0 + li)*KPAD + kk*32 + 8*g);
  f32x4 accW[5];
#pragma unroll
  for (int m = 0; m < 5; ++m) accW[m] = (f32x4){0.f, 0.f, 0.f, 0.f};
#pragma unroll 2
  for (int t = 0; t < 8; ++t) {
    const int jb = jbase + t*32;
    unsigned int (*Em)[36] = E_dw[t & 1][w];
#pragma unroll
    for (int m = 0; m < 2; ++m) {
      f32x4 acc = {0.f, 0.f, 0.f, 0.f};
#pragma unroll
      for (int kk = 0; kk < 3; ++kk) {
        short8v qa = *reinterpret_cast<const short8v*>(QB + (jb + m*16 + li)*KPAD + kk*32 + 8*g);
        acc = MFMA(qa, kb[kk], acc);
      }
      Em[li][m*8 + 2*g    ] = bf16pair(fexp2(acc[0]), fexp2(acc[1]));
      Em[li][m*8 + 2*g + 1] = bf16pair(fexp2(acc[2]), fexp2(acc[3]));
    }
    short8v eb = *reinterpret_cast<const short8v*>(&Em[li][4*g]);
#pragma unroll
    for (int m = 0; m < 5; ++m) {
      short8v wa = *reinterpret_cast<const short8v*>(WB + (m*16 + li)*NPIX + jb + 8*g);
      accW[m] = MFMA(wa, eb, accW[m]);
    }
  }
  // combine the 4 waves' accumulators (they cover disjoint j) in LDS
  if (w > 0) {
#pragma unroll
    for (int m = 0; m < 5; ++m) red[w-1][l][m] = accW[m];
  }
  __syncthreads();
  if (w == 0) {
#pragma unroll
    for (int o = 0; o < 3; ++o)
#pragma unroll
      for (int m = 0; m < 5; ++m) accW[m] += red[o][l][m];
    const int pbase[4] = { OFF_QC, OFF_VC, OFF_VG, OFF_OUTG };
    float* OP = ws + pbase[s];
#pragma unroll
    for (int m = 0; m < 5; ++m) {
#pragma unroll
      for (int r = 0; r < 4; ++r) {
        const int c = m*16 + 4*g + r;
        if (c < NCH) OP[(size_t)c*NPIX + i0 + li] = accW[m][r];
      }
    }
  }
}

// final: outC from moments; pooled = sum_c x*(outC + sum_s OUTGP[s]).  grid (288) x 256
__global__ void k_final(const float* __restrict__ x, const float* __restrict__ ws,
                        float* __restrict__ out)
{
  const int n = blockIdx.x >> 4;
  const int p = ((blockIdx.x & 15) << 8) + threadIdx.x;
  const float4 k = reinterpret_cast<const float4*>(ws + OFF_KC)[(size_t)n*NPIX + p];
  const float* M = ws + OFF_WM + n*64;
  float P[10];
  P[0] = k.x*k.x; P[1] = k.x*k.y; P[2] = k.x*k.z; P[3] = k.x*k.w;
  P[4] = k.y*k.y; P[5] = k.y*k.z; P[6] = k.y*k.w;
  P[7] = k.z*k.z; P[8] = k.z*k.w; P[9] = k.w*k.w;
  float s = 0.f;
#pragma unroll
  for (int c = 0; c < 4; ++c) {
    const float* mc = M + c*15;
    float oc = mc[0] + mc[1]*k.x + mc[2]*k.y + mc[3]*k.z + mc[4]*k.w;
#pragma unroll
    for (int i = 0; i < 10; ++i) oc += mc[5+i]*P[i];
    const size_t off = (size_t)(4*n + c)*NPIX + p;
    const float og = ws[OFF_QC + off] + ws[OFF_VC + off]
                   + ws[OFF_VG + off] + ws[OFF_OUTG + off];
    s += x[off] * (oc + og);
  }
  out[n*NPIX + p] = s;
}

extern "C" void kernel_launch(void* const* d_in, const int* in_sizes, int n_in,
                              void* d_out, int out_size, void* d_ws, size_t ws_size,
                              hipStream_t stream)
{
  const float* x   = (const float*)d_in[0];
  const float* Wq  = (const float*)d_in[1];
  const float* bq  = (const float*)d_in[2];
  const float* Wk  = (const float*)d_in[3];
  const float* bk  = (const float*)d_in[4];
  const float* Wv  = (const float*)d_in[5];
  const float* bv  = (const float*)d_in[6];
  const float* WqG = (const float*)d_in[7];
  const float* bqG = (const float*)d_in[8];
  const float* WkG = (const float*)d_in[9];
  const float* bkG = (const float*)d_in[10];
  const float* WvG = (const float*)d_in[11];
  const float* bvG = (const float*)d_in[12];
  float* ws  = (float*)d_ws;
  float* out = (float*)d_out;

  if (ws_size < (size_t)WS_FLOATS * sizeof(float)) return; // need ~8.2 MB scratch

  // no memsets: DG/SM/WM are zeroed inside k_qkv (kernel boundaries order the writes)
  hipLaunchKernelGGL(k_qkv, dim3(16, 24), dim3(256), 0, stream,
                     x, Wq, bq, Wk, bk, Wv, bv, WqG, bqG, WkG, bkG, WvG, bvG, ws);
  hipLaunchKernelGGL(k_kmom, dim3(4, 18), dim3(256), 0, stream, ws);
  hipLaunchKernelGGL(k_mA, dim3(64, 16), dim3(256), 0, stream, ws);
  hipLaunchKernelGGL(k_cmom, dim3(4, 18), dim3(256), 0, stream, ws);
  hipLaunchKernelGGL(k_wcompG, dim3(16), dim3(256), 0, stream, ws);
  hipLaunchKernelGGL(k_mB, dim3(256, 4), dim3(256), 0, stream, ws);
  hipLaunchKernelGGL(k_final, dim3(288), dim3(256), 0, stream, x, ws, out);
}